// Round 13
// baseline (159.083 us; speedup 1.0000x reference)
//
#include <hip/hip_runtime.h>
#include <hip/hip_bf16.h>

// B=2 H=16 S=2048 D=64, causal. Output = context (B,H,S,D) ++ attention (B,H,S,S), fp32.
// prep: fp32->bf16 pre-swizzled tile images in d_ws (64x64 tiles; Q/K row-major swz,
//       V transposed swz) -- unchanged from R7.
// main: 32-row q-tiles, 128-thread (2-wave) blocks, pair (pi, 63-pi) -> uniform 66
//       iters/block for ALL pi; grid 1024 -> 4 independent barrier domains per CU
//       (vs R7's 2). Per-wave inner loops identical to R7. XCD-pinned heads.

constexpr int SEQ = 2048;
constexpr int HD  = 64;
constexpr int NHEADS = 32;    // B*H
constexpr int NTK = 32;       // 64-key K-tiles
constexpr int NTQ = 64;       // 32-row Q-tiles

typedef __bf16 bf16x8 __attribute__((ext_vector_type(8)));
typedef unsigned short u16x8 __attribute__((ext_vector_type(8)));
typedef unsigned short u16x4 __attribute__((ext_vector_type(4)));
typedef float f32x4 __attribute__((ext_vector_type(4)));
typedef unsigned short us;

__device__ __forceinline__ us f2bf(float x) {
  unsigned u = __builtin_bit_cast(unsigned, x);
  return (us)((u + 0x7fffu + ((u >> 16) & 1u)) >> 16);  // RNE
}
__device__ __forceinline__ float bf2f(us b) {
  return __builtin_bit_cast(float, (unsigned)b << 16);
}

#define GLOAD_LDS(gp, lp)                                                        \
  __builtin_amdgcn_global_load_lds(                                             \
      (const __attribute__((address_space(1))) void*)(gp),                      \
      (__attribute__((address_space(3))) void*)(lp), 16, 0, 0)

// stage one 8KB tile image -> LDS with 128 threads: 2 waves x 4 calls x 64 lanes x 16B
__device__ __forceinline__ void stage8k_128(const us* img, us* lds, int t) {
  const char* g = (const char*)img + t * 16;
  char* s = (char*)lds + t * 16;
  GLOAD_LDS(g, s);
  GLOAD_LDS(g + 2048, s + 2048);
  GLOAD_LDS(g + 4096, s + 4096);
  GLOAD_LDS(g + 6144, s + 6144);
}

// ============ prep: build bf16 pre-swizzled tile images in scratch ============
// image elem (row r, col c) of Q/K 64x64 tile at u16-idx (r*64+c) ^ ((r&7)<<3)
// image elem V^T (d, key)                    at u16-idx (d*64+key) ^ ((d&7)<<3)
__global__ void prep_kernel(const float* __restrict__ Qg,
                            const float* __restrict__ Kg,
                            const float* __restrict__ Vg,
                            us* __restrict__ ws) {
  const int tile = blockIdx.x & (NTK - 1);
  const int bh   = blockIdx.x >> 5;
  const int t = threadIdx.x;
  const size_t tOff = ((size_t)bh * SEQ + (size_t)tile * 64) * HD;
  us* Qi = ws + ((size_t)bh * NTK + tile) * 4096;
  us* Ki = Qi + (size_t)NHEADS * NTK * 4096;
  us* Vi = Ki + (size_t)NHEADS * NTK * 4096;

  #pragma unroll
  for (int g0 = 0; g0 < 2; ++g0) {
    const int g = t + 256 * g0;          // 0..511 image chunks of 8 u16
    const int r = g >> 3, c8 = g & 7;
    const int cp = (8 * c8) ^ ((r & 7) << 3);   // source col for this chunk
    const float* qs = Qg + tOff + (size_t)r * HD + cp;
    const float* ks = Kg + tOff + (size_t)r * HD + cp;
    u16x8 q, k;
    #pragma unroll
    for (int j = 0; j < 8; ++j) { q[j] = f2bf(qs[j]); k[j] = f2bf(ks[j]); }
    *(u16x8*)(Qi + 8 * g) = q;
    *(u16x8*)(Ki + 8 * g) = k;
  }
  #pragma unroll
  for (int g0 = 0; g0 < 2; ++g0) {
    const int g = t + 256 * g0;
    const int d = g >> 3, k8 = g & 7;
    const int kp = (8 * k8) ^ ((d & 7) << 3);   // source key for this chunk
    const float* vs = Vg + tOff + d;
    u16x8 v;
    #pragma unroll
    for (int j = 0; j < 8; ++j) v[j] = f2bf(vs[(size_t)(kp + j) * HD]);
    *(u16x8*)(Vi + 8 * g) = v;
  }
}

// ======================= main attention kernel =======================
__launch_bounds__(128, 2)
__global__ void attn_main(const us* __restrict__ ws, float* __restrict__ out) {
  const int fb = blockIdx.x;            // 0..1023
  const int bh = fb & (NHEADS - 1);     // fb%8 == bh%8 -> head pinned to one XCD
  const int pi = fb >> 5;               // 0..31 pair: q-tiles pi and 63-pi (32-row)
  const int t  = threadIdx.x;           // 0..127
  const int l  = t & 63;
  const int w  = t >> 6;                // wave 0..1, owns q-rows w*16..w*16+15 of tile
  const int l16 = l & 15;
  const int lg  = l >> 4;

  __shared__ __align__(16) us Ks[2][4096];    // 64-key K tiles (b128-read swizzle)
  __shared__ __align__(16) us Vs[2][4096];    // V^T images
  __shared__ __align__(16) us Ps[2][1024];    // per-wave P strip [q=16][k=64]

  const us* Qi = ws + (size_t)bh * NTK * 4096;
  const us* Ki = Qi + (size_t)NHEADS * NTK * 4096;
  const us* Vi = Ki + (size_t)NHEADS * NTK * 4096;

  float* ctx = out + (size_t)bh * SEQ * HD;
  float* att = out + (size_t)NHEADS * SEQ * HD + (size_t)bh * SEQ * SEQ;

  const float KC = 0.18033688011112042f;  // (1/8) * log2(e)

  for (int half = 0; half < 2; ++half) {
    const int qt = half ? (NTQ - 1 - pi) : pi;   // 32-row q-tile index
    const int KT = qt >> 1;                      // last 64-key tile needed (inclusive)
    const int qbase = qt * 32;
    const int qg = qbase + w * 16 + l16;         // lane's q-row (S^T: col=l16)

    // ---- Q fragments from the 64-row image: tile qt/2, row (qt&1)*32 + ... ----
    bf16x8 aq[2];
    {
      const int qr = (qt & 1) * 32 + w * 16 + l16;   // row within the 64-row image
      const us* Qimg = Qi + (size_t)(qt >> 1) * 4096;
      #pragma unroll
      for (int ks = 0; ks < 2; ++ks) {
        const int idx = (qr * 64 + ks * 32 + lg * 8) ^ ((qr & 7) << 3);
        aq[ks] = __builtin_bit_cast(bf16x8, *(const u16x8*)(&Qimg[idx]));
      }
    }

    // ---- prologue: issue K0 stage; zero-fill masked cols; barrier ----
    stage8k_128(Ki, Ks[0], t);
    {
      const int zc0 = (KT + 1) * 64;              // phase 2 covers cols < zc0
      const int nz4 = (SEQ - zc0) >> 2;
      for (int rr = 0; rr < 32; ++rr) {
        float* rowp = att + (size_t)(qbase + rr) * SEQ + zc0;
        for (int c = t; c < nz4; c += 128)
          __builtin_nontemporal_store((f32x4){0.f, 0.f, 0.f, 0.f}, (f32x4*)(rowp + 4 * c));
      }
    }
    __syncthreads();

    // ================= phase 1: row sums =================
    float rsum = 0.f;
    {
      int cur = 0;
      for (int kt = 0; kt <= KT; ++kt) {
        if (kt < KT) stage8k_128(Ki + (size_t)(kt + 1) * 4096, Ks[cur ^ 1], t);
        const us* krb = Ks[cur];
        const int kb = kt * 64;
        #pragma unroll
        for (int ct = 0; ct < 4; ++ct) {
          f32x4 acc = {0.f, 0.f, 0.f, 0.f};
          #pragma unroll
          for (int ks = 0; ks < 2; ++ks) {
            const int kr = ct * 16 + l16;
            const int idx = (kr * 64 + ks * 32 + lg * 8) ^ ((kr & 7) << 3);
            bf16x8 bk = __builtin_bit_cast(bf16x8, *(const u16x8*)(&krb[idx]));
            acc = __builtin_amdgcn_mfma_f32_16x16x32_bf16(bk, aq[ks], acc, 0, 0, 0);
          }
          const int kg0 = kb + ct * 16 + lg * 4;
          #pragma unroll
          for (int rr = 0; rr < 4; ++rr) {
            float e = __builtin_amdgcn_exp2f(acc[rr] * KC);
            rsum += (kg0 + rr <= qg) ? e : 0.f;
          }
        }
        __syncthreads();   // drains staging (needed anyway; no stores in flight)
        cur ^= 1;
      }
    }
    // stage phase-2 tile 0 while reducing
    stage8k_128(Ki, Ks[0], t);
    stage8k_128(Vi, Vs[0], t);
    rsum += __shfl_xor(rsum, 16);
    rsum += __shfl_xor(rsum, 32);
    const float inv = 1.f / rsum;
    __syncthreads();

    // ================= phase 2: P -> att + O = P·V =================
    f32x4 oacc[4];
    #pragma unroll
    for (int ct = 0; ct < 4; ++ct) oacc[ct] = (f32x4){0.f, 0.f, 0.f, 0.f};

    {
      int cur = 0;
      for (int kt = 0; kt <= KT; ++kt) {
        if (kt < KT) {
          stage8k_128(Ki + (size_t)(kt + 1) * 4096, Ks[cur ^ 1], t);
          stage8k_128(Vi + (size_t)(kt + 1) * 4096, Vs[cur ^ 1], t);
        }
        const us* krb = Ks[cur];
        const us* vrb = Vs[cur];
        const int kb = kt * 64;

        // QK^T (swapped) -> normalized bf16 P into own-wave Ps
        #pragma unroll
        for (int ct = 0; ct < 4; ++ct) {
          f32x4 acc = {0.f, 0.f, 0.f, 0.f};
          #pragma unroll
          for (int ks = 0; ks < 2; ++ks) {
            const int kr = ct * 16 + l16;
            const int idx = (kr * 64 + ks * 32 + lg * 8) ^ ((kr & 7) << 3);
            bf16x8 bk = __builtin_bit_cast(bf16x8, *(const u16x8*)(&krb[idx]));
            acc = __builtin_amdgcn_mfma_f32_16x16x32_bf16(bk, aq[ks], acc, 0, 0, 0);
          }
          const int kg0 = kb + ct * 16 + lg * 4;
          u16x4 pb;
          #pragma unroll
          for (int rr = 0; rr < 4; ++rr) {
            float e = __builtin_amdgcn_exp2f(acc[rr] * KC) * inv;
            pb[rr] = f2bf((kg0 + rr <= qg) ? e : 0.f);
          }
          const int pidx = (l16 * 64 + ct * 16 + lg * 4) ^ ((l16 & 7) << 3);
          *(u16x4*)(&Ps[w][pidx]) = pb;
        }

        // att copy: own-wave rows, 256B/row contiguous, nontemporal (4 stores/lane)
        #pragma unroll
        for (int j = 0; j < 4; ++j) {
          const int rloc = lg + 4 * j;
          const int idx = (rloc * 64 + 4 * l16) ^ ((rloc & 7) << 3);
          u16x4 p4 = *(const u16x4*)(&Ps[w][idx]);
          f32x4 pv = { bf2f(p4[0]), bf2f(p4[1]), bf2f(p4[2]), bf2f(p4[3]) };
          __builtin_nontemporal_store(pv,
              (f32x4*)(att + (size_t)(qbase + w * 16 + rloc) * SEQ + kb + 4 * l16));
        }

        // PV (swapped): A = V^T via b128, B = P^T strip (own-wave)
        bf16x8 pa[2];
        #pragma unroll
        for (int ks = 0; ks < 2; ++ks) {
          const int pidx = (l16 * 64 + ks * 32 + lg * 8) ^ ((l16 & 7) << 3);
          pa[ks] = __builtin_bit_cast(bf16x8, *(const u16x8*)(&Ps[w][pidx]));
        }
        #pragma unroll
        for (int ct = 0; ct < 4; ++ct) {
          #pragma unroll
          for (int ks = 0; ks < 2; ++ks) {
            const int dr = ct * 16 + l16;
            const int vidx = (dr * 64 + ks * 32 + lg * 8) ^ ((dr & 7) << 3);
            bf16x8 av = __builtin_bit_cast(bf16x8, *(const u16x8*)(&vrb[vidx]));
            oacc[ct] = __builtin_amdgcn_mfma_f32_16x16x32_bf16(av, pa[ks], oacc[ct], 0, 0, 0);
          }
        }

        __syncthreads();
        cur ^= 1;
      }
    }

    // ---- context write: lane q=l16 row, d = ct*16+lg*4+rr ----
    #pragma unroll
    for (int ct = 0; ct < 4; ++ct)
      __builtin_nontemporal_store(oacc[ct],
          (f32x4*)(ctx + (size_t)qg * HD + ct * 16 + lg * 4));
  }
}

// ======================= fallback (R6, proven 153us) =======================
__launch_bounds__(256, 2)
__global__ void attn_fallback(const float* __restrict__ Qg,
                              const float* __restrict__ Kg,
                              const float* __restrict__ Vg,
                              float* __restrict__ out) {
  const int fb = blockIdx.x;
  const int bh = fb & (NHEADS - 1);
  const int pi = fb >> 5;
  const int t  = threadIdx.x;
  const int l  = t & 63;
  const int w  = t >> 6;
  const int l16 = l & 15;
  const int lg  = l >> 4;

  __shared__ __align__(16) us Qs[64 * HD];
  __shared__ __align__(16) us Ks[64 * HD];
  __shared__ __align__(16) us Vs[64 * HD];
  __shared__ __align__(16) us Ps[4][16 * 64];

  const size_t hoff = (size_t)bh * SEQ * HD;
  const float* Qh = Qg + hoff;
  const float* Kh = Kg + hoff;
  const float* Vh = Vg + hoff;
  float* ctx = out + hoff;
  float* att = out + (size_t)NHEADS * SEQ * HD + (size_t)bh * SEQ * SEQ;

  auto load_tile = [&](const float* src, f32x4 (&reg)[4]) {
    #pragma unroll
    for (int j = 0; j < 4; ++j) {
      const int f = t + 256 * j;
      reg[j] = *(const f32x4*)(src + (size_t)(f >> 4) * HD + 4 * (f & 15));
    }
  };
  auto write_k = [&](const f32x4 (&reg)[4], us* dst) {
    #pragma unroll
    for (int j = 0; j < 4; ++j) {
      const int f = t + 256 * j;
      const int rr = f >> 4, c4 = f & 15;
      const int idx = (rr * 64 + 4 * c4) ^ ((rr & 7) << 3);
      u16x4 b = { f2bf(reg[j].x), f2bf(reg[j].y), f2bf(reg[j].z), f2bf(reg[j].w) };
      *(u16x4*)(&dst[idx]) = b;
    }
  };
  auto write_vv = [&](const f32x4 (&reg)[4], us* dst) {
    #pragma unroll
    for (int j = 0; j < 4; ++j) {
      const int f = t + 256 * j;
      const int rr = f >> 4, c4 = f & 15;
      const int idx = (rr * 64 + 4 * c4) ^ (((rr >> 3) & 3) << 4);
      u16x4 b = { f2bf(reg[j].x), f2bf(reg[j].y), f2bf(reg[j].z), f2bf(reg[j].w) };
      *(u16x4*)(&dst[idx]) = b;
    }
  };

  const float sc = 0.125f;

  for (int half = 0; half < 2; ++half) {
    const int qt = half ? (31 - pi) : pi;
    const int qbase = qt * 64;
    const int qg = qbase + w * 16 + l16;

    __syncthreads();
    {
      const int zc0 = (qt + 1) * 64;
      const int nz4 = (SEQ - zc0) >> 2;
      for (int rr = 0; rr < 64; ++rr) {
        float* rowp = att + (size_t)(qbase + rr) * SEQ + zc0;
        for (int c = t; c < nz4; c += 256)
          __builtin_nontemporal_store((f32x4){0.f, 0.f, 0.f, 0.f}, (f32x4*)(rowp + 4 * c));
      }
    }
    {
      f32x4 qreg[4];
      load_tile(Qh + (size_t)qbase * HD, qreg);
      write_k(qreg, Qs);
    }
    __syncthreads();

    bf16x8 aq[2];
    #pragma unroll
    for (int ks = 0; ks < 2; ++ks) {
      const int qr = w * 16 + l16;
      const int idx = (qr * 64 + ks * 32 + lg * 8) ^ ((qr & 7) << 3);
      aq[ks] = __builtin_bit_cast(bf16x8, *(const u16x8*)(&Qs[idx]));
    }

    float rsum = 0.f;
    {
      f32x4 kreg[4];
      load_tile(Kh, kreg);
      write_k(kreg, Ks);
      __syncthreads();
      for (int kt = 0; kt <= qt; ++kt) {
        if (kt < qt) load_tile(Kh + (size_t)(kt + 1) * 64 * HD, kreg);
        const int kb = kt * 64;
        #pragma unroll
        for (int ct = 0; ct < 4; ++ct) {
          f32x4 acc = {0.f, 0.f, 0.f, 0.f};
          #pragma unroll
          for (int ks = 0; ks < 2; ++ks) {
            const int kr = ct * 16 + l16;
            const int idx = (kr * 64 + ks * 32 + lg * 8) ^ ((kr & 7) << 3);
            bf16x8 bk = __builtin_bit_cast(bf16x8, *(const u16x8*)(&Ks[idx]));
            acc = __builtin_amdgcn_mfma_f32_16x16x32_bf16(bk, aq[ks], acc, 0, 0, 0);
          }
          const int kg0 = kb + ct * 16 + lg * 4;
          #pragma unroll
          for (int rr = 0; rr < 4; ++rr) {
            float e = __expf(acc[rr] * sc);
            rsum += (kg0 + rr <= qg) ? e : 0.f;
          }
        }
        __syncthreads();
        if (kt < qt) write_k(kreg, Ks);
        __syncthreads();
      }
    }
    rsum += __shfl_xor(rsum, 16);
    rsum += __shfl_xor(rsum, 32);
    const float inv = 1.f / rsum;

    f32x4 oacc[4];
    #pragma unroll
    for (int ct = 0; ct < 4; ++ct) oacc[ct] = (f32x4){0.f, 0.f, 0.f, 0.f};

    {
      f32x4 kreg[4], vreg[4];
      load_tile(Kh, kreg);
      load_tile(Vh, vreg);
      write_k(kreg, Ks);
      write_vv(vreg, Vs);
      __syncthreads();
      for (int kt = 0; kt <= qt; ++kt) {
        if (kt < qt) {
          load_tile(Kh + (size_t)(kt + 1) * 64 * HD, kreg);
          load_tile(Vh + (size_t)(kt + 1) * 64 * HD, vreg);
        }
        const int kb = kt * 64;
        #pragma unroll
        for (int ct = 0; ct < 4; ++ct) {
          f32x4 acc = {0.f, 0.f, 0.f, 0.f};
          #pragma unroll
          for (int ks = 0; ks < 2; ++ks) {
            const int kr = ct * 16 + l16;
            const int idx = (kr * 64 + ks * 32 + lg * 8) ^ ((kr & 7) << 3);
            bf16x8 bk = __builtin_bit_cast(bf16x8, *(const u16x8*)(&Ks[idx]));
            acc = __builtin_amdgcn_mfma_f32_16x16x32_bf16(bk, aq[ks], acc, 0, 0, 0);
          }
          const int kg0 = kb + ct * 16 + lg * 4;
          u16x4 pb;
          #pragma unroll
          for (int rr = 0; rr < 4; ++rr) {
            float e = __expf(acc[rr] * sc) * inv;
            pb[rr] = f2bf((kg0 + rr <= qg) ? e : 0.f);
          }
          const int pidx = (l16 * 64 + ct * 16 + lg * 4) ^ ((l16 & 7) << 3);
          *(u16x4*)(&Ps[w][pidx]) = pb;
        }
        #pragma unroll
        for (int ct = 0; ct < 4; ++ct) {
          #pragma unroll
          for (int ks = 0; ks < 2; ++ks) {
            const int key0 = ks * 32 + lg * 8;
            const int pidx = (l16 * 64 + key0) ^ ((l16 & 7) << 3);
            bf16x8 pa = __builtin_bit_cast(bf16x8, *(const u16x8*)(&Ps[w][pidx]));
            bf16x8 av;
            const int dcol = ct * 16 + l16;
            const int xorv = ((key0 >> 3) & 3) << 4;
            #pragma unroll
            for (int j = 0; j < 8; ++j)
              av[j] = __builtin_bit_cast(__bf16, Vs[((key0 + j) * 64 + dcol) ^ xorv]);
            oacc[ct] = __builtin_amdgcn_mfma_f32_16x16x32_bf16(av, pa, oacc[ct], 0, 0, 0);
          }
        }
        __syncthreads();
        #pragma unroll
        for (int j = 0; j < 4; ++j) {
          const int f = t + 256 * j;
          const int rr = f >> 4, c4 = f & 15;
          const int ww = rr >> 4, qr = rr & 15;
          const int idx = (qr * 64 + 4 * c4) ^ ((qr & 7) << 3);
          u16x4 pb = *(const u16x4*)(&Ps[ww][idx]);
          f32x4 pv = { bf2f(pb[0]), bf2f(pb[1]), bf2f(pb[2]), bf2f(pb[3]) };
          __builtin_nontemporal_store(pv,
              (f32x4*)(att + (size_t)(qbase + rr) * SEQ + kb + 4 * c4));
        }
        if (kt < qt) {
          write_k(kreg, Ks);
          write_vv(vreg, Vs);
        }
        __syncthreads();
      }
    }
    #pragma unroll
    for (int ct = 0; ct < 4; ++ct)
      *(f32x4*)(ctx + (size_t)qg * HD + ct * 16 + lg * 4) = oacc[ct];
  }
}

extern "C" void kernel_launch(void* const* d_in, const int* in_sizes, int n_in,
                              void* d_out, int out_size, void* d_ws, size_t ws_size,
                              hipStream_t stream) {
  const float* Q = (const float*)d_in[0];
  const float* K = (const float*)d_in[1];
  const float* V = (const float*)d_in[2];
  float* out = (float*)d_out;
  const size_t NEED = (size_t)3 * NHEADS * NTK * 4096 * sizeof(us);  // 25.2 MB
  if (ws_size >= NEED && d_ws != nullptr) {
    us* wsp = (us*)d_ws;
    prep_kernel<<<dim3(NHEADS * NTK), dim3(256), 0, stream>>>(Q, K, V, wsp);
    attn_main<<<dim3(NTQ / 2 * NHEADS), dim3(128), 0, stream>>>(wsp, out);
  } else {
    attn_fallback<<<dim3(16 * NHEADS), dim3(256), 0, stream>>>(Q, K, V, out);
  }
}

// Round 14
// 142.464 us; speedup vs baseline: 1.1167x; 1.1167x over previous
//
#include <hip/hip_runtime.h>
#include <hip/hip_bf16.h>

// B=2 H=16 S=2048 D=64, causal. Output = context (B,H,S,D) ++ attention (B,H,S,S), fp32.
// CHAMPION (R7, 142us) restored verbatim.
// prep: fp32->bf16 pre-swizzled LDS images in d_ws (K/Q row-major swz, V transposed swz).
// main: uniform-work pair blocks (pi, 31-pi), XCD-pinned heads (fb%8==bh%8),
//       global_load_lds(16B) dbuf staging, b128 PV reads, 1 barrier/iter.

constexpr int SEQ = 2048;
constexpr int HD  = 64;
constexpr int NHEADS = 32;   // B*H
constexpr int QT  = 64;
constexpr int NT  = SEQ / QT;

typedef __bf16 bf16x8 __attribute__((ext_vector_type(8)));
typedef unsigned short u16x8 __attribute__((ext_vector_type(8)));
typedef unsigned short u16x4 __attribute__((ext_vector_type(4)));
typedef float f32x4 __attribute__((ext_vector_type(4)));
typedef unsigned short us;

__device__ __forceinline__ us f2bf(float x) {
  unsigned u = __builtin_bit_cast(unsigned, x);
  return (us)((u + 0x7fffu + ((u >> 16) & 1u)) >> 16);  // RNE
}
__device__ __forceinline__ float bf2f(us b) {
  return __builtin_bit_cast(float, (unsigned)b << 16);
}

#define GLOAD_LDS(gp, lp)                                                        \
  __builtin_amdgcn_global_load_lds(                                             \
      (const __attribute__((address_space(1))) void*)(gp),                      \
      (__attribute__((address_space(3))) void*)(lp), 16, 0, 0)

// stage one 8KB tile image -> LDS: 4 waves x 2 calls x 64 lanes x 16B
__device__ __forceinline__ void stage8k(const us* img, us* lds, int w, int l) {
  const char* g = (const char*)img + w * 2048 + l * 16;
  char* s = (char*)lds + w * 2048;
  GLOAD_LDS(g, s);
  GLOAD_LDS(g + 1024, s + 1024);
}

// ============ prep: build bf16 pre-swizzled tile images in scratch ============
// image elem (row r, col c) of Q/K tile at u16-idx (r*64+c) ^ ((r&7)<<3)
// image elem V^T (d, key)            at u16-idx (d*64+key) ^ ((d&7)<<3)
__global__ void prep_kernel(const float* __restrict__ Qg,
                            const float* __restrict__ Kg,
                            const float* __restrict__ Vg,
                            us* __restrict__ ws) {
  const int tile = blockIdx.x & (NT - 1);
  const int bh   = blockIdx.x >> 5;
  const int t = threadIdx.x;
  const size_t tOff = ((size_t)bh * SEQ + (size_t)tile * QT) * HD;
  us* Qi = ws + ((size_t)bh * NT + tile) * 4096;
  us* Ki = Qi + (size_t)NHEADS * NT * 4096;
  us* Vi = Ki + (size_t)NHEADS * NT * 4096;

  #pragma unroll
  for (int g0 = 0; g0 < 2; ++g0) {
    const int g = t + 256 * g0;          // 0..511 image chunks of 8 u16
    const int r = g >> 3, c8 = g & 7;
    const int cp = (8 * c8) ^ ((r & 7) << 3);   // source col for this chunk
    const float* qs = Qg + tOff + (size_t)r * HD + cp;
    const float* ks = Kg + tOff + (size_t)r * HD + cp;
    u16x8 q, k;
    #pragma unroll
    for (int j = 0; j < 8; ++j) { q[j] = f2bf(qs[j]); k[j] = f2bf(ks[j]); }
    *(u16x8*)(Qi + 8 * g) = q;
    *(u16x8*)(Ki + 8 * g) = k;
  }
  #pragma unroll
  for (int g0 = 0; g0 < 2; ++g0) {
    const int g = t + 256 * g0;
    const int d = g >> 3, k8 = g & 7;
    const int kp = (8 * k8) ^ ((d & 7) << 3);   // source key for this chunk
    const float* vs = Vg + tOff + d;
    u16x8 v;
    #pragma unroll
    for (int j = 0; j < 8; ++j) v[j] = f2bf(vs[(size_t)(kp + j) * HD]);
    *(u16x8*)(Vi + 8 * g) = v;
  }
}

// ======================= main attention kernel =======================
__launch_bounds__(256, 3)
__global__ void attn_main(const us* __restrict__ ws, float* __restrict__ out) {
  const int fb = blockIdx.x;
  const int bh = fb & (NHEADS - 1);   // fb%8==bh%8 -> head pinned to one XCD
  const int pi = fb >> 5;             // 0..15 pair index
  const int t  = threadIdx.x;
  const int l  = t & 63;
  const int w  = t >> 6;
  const int l16 = l & 15;
  const int lg  = l >> 4;

  __shared__ __align__(16) us Qs[4096];
  __shared__ __align__(16) us Ks[2][4096];
  __shared__ __align__(16) us Vs[2][4096];     // V^T images
  __shared__ __align__(16) us Ps[4][1024];     // per-wave P strip [q=16][k=64]

  const us* Qi = ws + (size_t)bh * NT * 4096;
  const us* Ki = Qi + (size_t)NHEADS * NT * 4096;
  const us* Vi = Ki + (size_t)NHEADS * NT * 4096;

  float* ctx = out + (size_t)bh * SEQ * HD;
  float* att = out + (size_t)NHEADS * SEQ * HD + (size_t)bh * SEQ * SEQ;

  const float KC = 0.18033688011112042f;  // (1/8) * log2(e)

  for (int half = 0; half < 2; ++half) {
    const int qt = half ? (NT - 1 - pi) : pi;
    const int qbase = qt * QT;
    const int qg = qbase + w * 16 + l16;     // lane's q-row (S^T: col=l16)

    // issue Q + first K stage, overlap with zero-fill stores, then one barrier
    stage8k(Qi + (size_t)qt * 4096, Qs, w, l);
    stage8k(Ki, Ks[0], w, l);
    {
      const int zc0 = (qt + 1) * QT;
      const int nz4 = (SEQ - zc0) >> 2;
      for (int r = 0; r < QT; ++r) {
        float* rowp = att + (size_t)(qbase + r) * SEQ + zc0;
        for (int c = t; c < nz4; c += 256)
          __builtin_nontemporal_store((f32x4){0.f, 0.f, 0.f, 0.f}, (f32x4*)(rowp + 4 * c));
      }
    }
    __syncthreads();

    bf16x8 aq[2];
    #pragma unroll
    for (int ks = 0; ks < 2; ++ks) {
      const int qr = w * 16 + l16;
      const int d0 = ks * 32 + lg * 8;
      const int idx = (qr * 64 + d0) ^ ((qr & 7) << 3);
      aq[ks] = __builtin_bit_cast(bf16x8, *(const u16x8*)(&Qs[idx]));
    }

    // ================= phase 1: row sums =================
    float rsum = 0.f;
    {
      int cur = 0;
      for (int kt = 0; kt <= qt; ++kt) {
        if (kt < qt) stage8k(Ki + (size_t)(kt + 1) * 4096, Ks[cur ^ 1], w, l);
        const us* krb = Ks[cur];
        const int kb = kt * QT;
        #pragma unroll
        for (int ct = 0; ct < 4; ++ct) {
          f32x4 acc = {0.f, 0.f, 0.f, 0.f};
          #pragma unroll
          for (int ks = 0; ks < 2; ++ks) {
            const int kr = ct * 16 + l16;
            const int d0 = ks * 32 + lg * 8;
            const int idx = (kr * 64 + d0) ^ ((kr & 7) << 3);
            bf16x8 bk = __builtin_bit_cast(bf16x8, *(const u16x8*)(&krb[idx]));
            acc = __builtin_amdgcn_mfma_f32_16x16x32_bf16(bk, aq[ks], acc, 0, 0, 0);
          }
          const int kg0 = kb + ct * 16 + lg * 4;
          #pragma unroll
          for (int r = 0; r < 4; ++r) {
            float e = __builtin_amdgcn_exp2f(acc[r] * KC);
            rsum += (kg0 + r <= qg) ? e : 0.f;
          }
        }
        __syncthreads();
        cur ^= 1;
      }
    }
    // stage phase-2 tile 0 while reducing
    stage8k(Ki, Ks[0], w, l);
    stage8k(Vi, Vs[0], w, l);
    rsum += __shfl_xor(rsum, 16);
    rsum += __shfl_xor(rsum, 32);
    const float inv = 1.f / rsum;
    __syncthreads();

    // ================= phase 2: P -> att + O = P·V =================
    f32x4 oacc[4];
    #pragma unroll
    for (int ct = 0; ct < 4; ++ct) oacc[ct] = (f32x4){0.f, 0.f, 0.f, 0.f};

    {
      int cur = 0;
      for (int kt = 0; kt <= qt; ++kt) {
        if (kt < qt) {
          stage8k(Ki + (size_t)(kt + 1) * 4096, Ks[cur ^ 1], w, l);
          stage8k(Vi + (size_t)(kt + 1) * 4096, Vs[cur ^ 1], w, l);
        }
        const us* krb = Ks[cur];
        const us* vrb = Vs[cur];
        const int kb = kt * QT;

        // QK^T (swapped) -> normalized bf16 P into own-wave Ps
        #pragma unroll
        for (int ct = 0; ct < 4; ++ct) {
          f32x4 acc = {0.f, 0.f, 0.f, 0.f};
          #pragma unroll
          for (int ks = 0; ks < 2; ++ks) {
            const int kr = ct * 16 + l16;
            const int d0 = ks * 32 + lg * 8;
            const int idx = (kr * 64 + d0) ^ ((kr & 7) << 3);
            bf16x8 bk = __builtin_bit_cast(bf16x8, *(const u16x8*)(&krb[idx]));
            acc = __builtin_amdgcn_mfma_f32_16x16x32_bf16(bk, aq[ks], acc, 0, 0, 0);
          }
          const int kg0 = kb + ct * 16 + lg * 4;
          u16x4 pb;
          #pragma unroll
          for (int r = 0; r < 4; ++r) {
            float e = __builtin_amdgcn_exp2f(acc[r] * KC) * inv;
            pb[r] = f2bf((kg0 + r <= qg) ? e : 0.f);
          }
          const int pidx = (l16 * 64 + ct * 16 + lg * 4) ^ ((l16 & 7) << 3);
          *(u16x4*)(&Ps[w][pidx]) = pb;
        }

        // att copy: own-wave rows, 256B/row contiguous, nontemporal
        #pragma unroll
        for (int j = 0; j < 4; ++j) {
          const int rloc = lg + 4 * j;
          const int idx = (rloc * 64 + 4 * l16) ^ ((rloc & 7) << 3);
          u16x4 p4 = *(const u16x4*)(&Ps[w][idx]);
          f32x4 pv = { bf2f(p4[0]), bf2f(p4[1]), bf2f(p4[2]), bf2f(p4[3]) };
          __builtin_nontemporal_store(pv,
              (f32x4*)(att + (size_t)(qbase + w * 16 + rloc) * SEQ + kb + 4 * l16));
        }

        // PV (swapped): A = V^T via b128 (same pattern as K reads), B = P^T strip
        bf16x8 pa[2];
        #pragma unroll
        for (int ks = 0; ks < 2; ++ks) {
          const int pidx = (l16 * 64 + ks * 32 + lg * 8) ^ ((l16 & 7) << 3);
          pa[ks] = __builtin_bit_cast(bf16x8, *(const u16x8*)(&Ps[w][pidx]));
        }
        #pragma unroll
        for (int ct = 0; ct < 4; ++ct) {
          #pragma unroll
          for (int ks = 0; ks < 2; ++ks) {
            const int dr = ct * 16 + l16;
            const int key0 = ks * 32 + lg * 8;
            const int vidx = (dr * 64 + key0) ^ ((dr & 7) << 3);
            bf16x8 av = __builtin_bit_cast(bf16x8, *(const u16x8*)(&vrb[vidx]));
            oacc[ct] = __builtin_amdgcn_mfma_f32_16x16x32_bf16(av, pa[ks], oacc[ct], 0, 0, 0);
          }
        }

        __syncthreads();
        cur ^= 1;
      }
    }

    // ---- context write: lane q=l16 row, d = ct*16+lg*4+r ----
    #pragma unroll
    for (int ct = 0; ct < 4; ++ct)
      __builtin_nontemporal_store(oacc[ct],
          (f32x4*)(ctx + (size_t)qg * HD + ct * 16 + lg * 4));
  }
}

// ======================= fallback (R6, proven 153us) =======================
__launch_bounds__(256, 2)
__global__ void attn_fallback(const float* __restrict__ Qg,
                              const float* __restrict__ Kg,
                              const float* __restrict__ Vg,
                              float* __restrict__ out) {
  const int fb = blockIdx.x;
  const int bh = fb & (NHEADS - 1);
  const int pi = fb >> 5;
  const int t  = threadIdx.x;
  const int l  = t & 63;
  const int w  = t >> 6;
  const int l16 = l & 15;
  const int lg  = l >> 4;

  __shared__ __align__(16) us Qs[QT * HD];
  __shared__ __align__(16) us Ks[QT * HD];
  __shared__ __align__(16) us Vs[QT * HD];
  __shared__ __align__(16) us Ps[4][16 * QT];

  const size_t hoff = (size_t)bh * SEQ * HD;
  const float* Qh = Qg + hoff;
  const float* Kh = Kg + hoff;
  const float* Vh = Vg + hoff;
  float* ctx = out + hoff;
  float* att = out + (size_t)NHEADS * SEQ * HD + (size_t)bh * SEQ * SEQ;

  auto load_tile = [&](const float* src, f32x4 (&reg)[4]) {
    #pragma unroll
    for (int j = 0; j < 4; ++j) {
      const int f = t + 256 * j;
      reg[j] = *(const f32x4*)(src + (size_t)(f >> 4) * HD + 4 * (f & 15));
    }
  };
  auto write_k = [&](const f32x4 (&reg)[4], us* dst) {
    #pragma unroll
    for (int j = 0; j < 4; ++j) {
      const int f = t + 256 * j;
      const int rr = f >> 4, c4 = f & 15;
      const int idx = (rr * 64 + 4 * c4) ^ ((rr & 7) << 3);
      u16x4 b = { f2bf(reg[j].x), f2bf(reg[j].y), f2bf(reg[j].z), f2bf(reg[j].w) };
      *(u16x4*)(&dst[idx]) = b;
    }
  };
  auto write_vv = [&](const f32x4 (&reg)[4], us* dst) {
    #pragma unroll
    for (int j = 0; j < 4; ++j) {
      const int f = t + 256 * j;
      const int rr = f >> 4, c4 = f & 15;
      const int idx = (rr * 64 + 4 * c4) ^ (((rr >> 3) & 3) << 4);
      u16x4 b = { f2bf(reg[j].x), f2bf(reg[j].y), f2bf(reg[j].z), f2bf(reg[j].w) };
      *(u16x4*)(&dst[idx]) = b;
    }
  };

  const float sc = 0.125f;

  for (int half = 0; half < 2; ++half) {
    const int qt = half ? (NT - 1 - pi) : pi;
    const int qbase = qt * QT;
    const int qg = qbase + w * 16 + l16;

    __syncthreads();
    {
      const int zc0 = (qt + 1) * QT;
      const int nz4 = (SEQ - zc0) >> 2;
      for (int rr = 0; rr < QT; ++rr) {
        float* rowp = att + (size_t)(qbase + rr) * SEQ + zc0;
        for (int c = t; c < nz4; c += 256)
          __builtin_nontemporal_store((f32x4){0.f, 0.f, 0.f, 0.f}, (f32x4*)(rowp + 4 * c));
      }
    }
    {
      f32x4 qreg[4];
      load_tile(Qh + (size_t)qbase * HD, qreg);
      write_k(qreg, Qs);
    }
    __syncthreads();

    bf16x8 aq[2];
    #pragma unroll
    for (int ks = 0; ks < 2; ++ks) {
      const int qr = w * 16 + l16;
      const int idx = (qr * 64 + ks * 32 + lg * 8) ^ ((qr & 7) << 3);
      aq[ks] = __builtin_bit_cast(bf16x8, *(const u16x8*)(&Qs[idx]));
    }

    float rsum = 0.f;
    {
      f32x4 kreg[4];
      load_tile(Kh, kreg);
      write_k(kreg, Ks);
      __syncthreads();
      for (int kt = 0; kt <= qt; ++kt) {
        if (kt < qt) load_tile(Kh + (size_t)(kt + 1) * QT * HD, kreg);
        const int kb = kt * QT;
        #pragma unroll
        for (int ct = 0; ct < 4; ++ct) {
          f32x4 acc = {0.f, 0.f, 0.f, 0.f};
          #pragma unroll
          for (int ks = 0; ks < 2; ++ks) {
            const int kr = ct * 16 + l16;
            const int idx = (kr * 64 + ks * 32 + lg * 8) ^ ((kr & 7) << 3);
            bf16x8 bk = __builtin_bit_cast(bf16x8, *(const u16x8*)(&Ks[idx]));
            acc = __builtin_amdgcn_mfma_f32_16x16x32_bf16(bk, aq[ks], acc, 0, 0, 0);
          }
          const int kg0 = kb + ct * 16 + lg * 4;
          #pragma unroll
          for (int rr = 0; rr < 4; ++rr) {
            float e = __expf(acc[rr] * sc);
            rsum += (kg0 + rr <= qg) ? e : 0.f;
          }
        }
        __syncthreads();
        if (kt < qt) write_k(kreg, Ks);
        __syncthreads();
      }
    }
    rsum += __shfl_xor(rsum, 16);
    rsum += __shfl_xor(rsum, 32);
    const float inv = 1.f / rsum;

    f32x4 oacc[4];
    #pragma unroll
    for (int ct = 0; ct < 4; ++ct) oacc[ct] = (f32x4){0.f, 0.f, 0.f, 0.f};

    {
      f32x4 kreg[4], vreg[4];
      load_tile(Kh, kreg);
      load_tile(Vh, vreg);
      write_k(kreg, Ks);
      write_vv(vreg, Vs);
      __syncthreads();
      for (int kt = 0; kt <= qt; ++kt) {
        if (kt < qt) {
          load_tile(Kh + (size_t)(kt + 1) * QT * HD, kreg);
          load_tile(Vh + (size_t)(kt + 1) * QT * HD, vreg);
        }
        const int kb = kt * QT;
        #pragma unroll
        for (int ct = 0; ct < 4; ++ct) {
          f32x4 acc = {0.f, 0.f, 0.f, 0.f};
          #pragma unroll
          for (int ks = 0; ks < 2; ++ks) {
            const int kr = ct * 16 + l16;
            const int idx = (kr * 64 + ks * 32 + lg * 8) ^ ((kr & 7) << 3);
            bf16x8 bk = __builtin_bit_cast(bf16x8, *(const u16x8*)(&Ks[idx]));
            acc = __builtin_amdgcn_mfma_f32_16x16x32_bf16(bk, aq[ks], acc, 0, 0, 0);
          }
          const int kg0 = kb + ct * 16 + lg * 4;
          u16x4 pb;
          #pragma unroll
          for (int rr = 0; rr < 4; ++rr) {
            float e = __expf(acc[rr] * sc) * inv;
            pb[rr] = f2bf((kg0 + rr <= qg) ? e : 0.f);
          }
          const int pidx = (l16 * 64 + ct * 16 + lg * 4) ^ ((l16 & 7) << 3);
          *(u16x4*)(&Ps[w][pidx]) = pb;
        }
        #pragma unroll
        for (int ct = 0; ct < 4; ++ct) {
          #pragma unroll
          for (int ks = 0; ks < 2; ++ks) {
            const int key0 = ks * 32 + lg * 8;
            const int pidx = (l16 * 64 + key0) ^ ((l16 & 7) << 3);
            bf16x8 pa = __builtin_bit_cast(bf16x8, *(const u16x8*)(&Ps[w][pidx]));
            bf16x8 av;
            const int dcol = ct * 16 + l16;
            const int xorv = ((key0 >> 3) & 3) << 4;
            #pragma unroll
            for (int j = 0; j < 8; ++j)
              av[j] = __builtin_bit_cast(__bf16, Vs[((key0 + j) * 64 + dcol) ^ xorv]);
            oacc[ct] = __builtin_amdgcn_mfma_f32_16x16x32_bf16(av, pa, oacc[ct], 0, 0, 0);
          }
        }
        __syncthreads();
        #pragma unroll
        for (int j = 0; j < 4; ++j) {
          const int f = t + 256 * j;
          const int rr = f >> 4, c4 = f & 15;
          const int ww = rr >> 4, qr = rr & 15;
          const int idx = (qr * 64 + 4 * c4) ^ ((qr & 7) << 3);
          u16x4 pb = *(const u16x4*)(&Ps[ww][idx]);
          f32x4 pv = { bf2f(pb[0]), bf2f(pb[1]), bf2f(pb[2]), bf2f(pb[3]) };
          __builtin_nontemporal_store(pv,
              (f32x4*)(att + (size_t)(qbase + rr) * SEQ + kb + 4 * c4));
        }
        if (kt < qt) {
          write_k(kreg, Ks);
          write_vv(vreg, Vs);
        }
        __syncthreads();
      }
    }
    #pragma unroll
    for (int ct = 0; ct < 4; ++ct)
      *(f32x4*)(ctx + (size_t)qg * HD + ct * 16 + lg * 4) = oacc[ct];
  }
}

extern "C" void kernel_launch(void* const* d_in, const int* in_sizes, int n_in,
                              void* d_out, int out_size, void* d_ws, size_t ws_size,
                              hipStream_t stream) {
  const float* Q = (const float*)d_in[0];
  const float* K = (const float*)d_in[1];
  const float* V = (const float*)d_in[2];
  float* out = (float*)d_out;
  const size_t NEED = (size_t)3 * NHEADS * NT * 4096 * sizeof(us);  // 25.2 MB
  if (ws_size >= NEED && d_ws != nullptr) {
    us* wsp = (us*)d_ws;
    prep_kernel<<<dim3(NHEADS * NT), dim3(256), 0, stream>>>(Q, K, V, wsp);
    attn_main<<<dim3(NT / 2 * NHEADS), dim3(256), 0, stream>>>(wsp, out);
  } else {
    attn_fallback<<<dim3(NT / 2 * NHEADS), dim3(256), 0, stream>>>(Q, K, V, out);
  }
}